// Round 4
// baseline (207.933 us; speedup 1.0000x reference)
//
#include <hip/hip_runtime.h>

// mRNN B=128, C=64, H=32, T=256 via MFMA 16x16x32 bf16, split-bf16 (hi+lo).
// One block per (c, batch-group-16): 512 blocks x 128 threads.
// wave0 = forward scan, wave1 = backward scan, partials staged in LDS,
// combine + final store fused into the same kernel (no ws round-trip).
//
// Layout-closed recurrence (round-3 verified): h kept as the B-operand
// fragment; row permutation rho(m)=8*(m>>2)+(m&3) (+4 for tile1) makes lane
// (q,n)'s C/D values exactly its next-step B fragment. No LDS / cross-lane
// traffic inside the recurrence.
//
// Precision: W=Whi+Wlo, h=hhi+hlo (hi=truncate -> exact residual, lo=RNE via
// +0x8000). D = (Whi@hhi + vinit) + (Wlo@hhi + Whi@hlo); dropped lo@lo term
// ~2^-17 relative/step. V-term + bias + U-projection in exact fp32.
constexpr int Bn = 128, Cn = 64, Hn = 32, Tn = 256;

typedef __attribute__((ext_vector_type(8))) short short8;
typedef __attribute__((ext_vector_type(4))) float f32x4;
typedef __attribute__((ext_vector_type(4))) unsigned int u32x4;

// pack top16(y):top16(x) -> one u32 (low half = x's top16)
__device__ __forceinline__ unsigned pk_hi(unsigned y, unsigned x) {
  return __builtin_amdgcn_perm(y, x, 0x07060302u);
}

__device__ __forceinline__ void wsplit(float w, short& hi, short& lo) {
  unsigned u = __float_as_uint(w);
  float r = w - __uint_as_float(u & 0xffff0000u);   // exact residual
  unsigned ru = __float_as_uint(r) + 0x8000u;       // round-to-nearest lo
  hi = (short)(u >> 16);
  lo = (short)(ru >> 16);
}

__global__ __launch_bounds__(128)
void mrnn_fused(const float* __restrict__ x, const float* __restrict__ m,
                const float* __restrict__ d,
                const float* __restrict__ Wf, const float* __restrict__ Vf,
                const float* __restrict__ cf,
                const float* __restrict__ Wb, const float* __restrict__ Vb,
                const float* __restrict__ cb,
                const float* __restrict__ U, const float* __restrict__ c0,
                float* __restrict__ out) {
  const int bid = blockIdx.x;          // 512 blocks
  const int c   = bid >> 3;
  const int g   = bid & 7;
  const int tid = threadIdx.x;         // 0..127
  const int dir  = tid >> 6;           // wave0 fwd, wave1 bwd
  const int lane = tid & 63;
  const int q = lane >> 4;
  const int n = lane & 15;
  const int b = g * 16 + n;

  // partial projections: [dir][n][t], stride 260 (+4 pad -> bank rotation)
  __shared__ __align__(16) float pbuf[2][16][260];

  const float* W  = dir ? Wb : Wf;
  const float* V  = dir ? Vb : Vf;
  const float* cc = dir ? cb : cf;

  // ---- A fragments: A[m=lane&15][k=8q+j], row perm rho(m)=8*(m>>2)+(m&3)
  const int ra0 = 8 * (n >> 2) + (n & 3);
  const int ra1 = ra0 + 4;
  short8 A0h, A0l, A1h, A1l;
#pragma unroll
  for (int j = 0; j < 8; ++j) {
    short hi, lo;
    wsplit(W[(c * Hn + ra0) * Hn + 8 * q + j], hi, lo); A0h[j] = hi; A0l[j] = lo;
    wsplit(W[(c * Hn + ra1) * Hn + 8 * q + j], hi, lo); A1h[j] = hi; A1l[j] = lo;
  }

  // ---- per-lane D rows: tile0 -> 8q+r, tile1 -> 8q+4+r
  float v0x[4], v0y[4], v0z[4], bs0[4], uu0[4];
  float v1x[4], v1y[4], v1z[4], bs1[4], uu1[4];
#pragma unroll
  for (int r = 0; r < 4; ++r) {
    const int row0 = 8 * q + r, row1 = row0 + 4;
    const float* vp0 = V + (c * Hn + row0) * 3;
    v0x[r] = vp0[0]; v0y[r] = vp0[1]; v0z[r] = vp0[2];
    bs0[r] = cc[c * Hn + row0];
    uu0[r] = U[c * 2 * Hn + dir * Hn + row0];
    const float* vp1 = V + (c * Hn + row1) * 3;
    v1x[r] = vp1[0]; v1y[r] = vp1[1]; v1z[r] = vp1[2];
    bs1[r] = cc[c * Hn + row1];
    uu1[r] = U[c * 2 * Hn + dir * Hn + row1];
  }

  // ---- state (B fragments) as raw u32x4, bit_cast at MFMA call
  u32x4 Bh = {0u, 0u, 0u, 0u};
  u32x4 Bl = {0u, 0u, 0u, 0u};
  const f32x4 z4 = {0.f, 0.f, 0.f, 0.f};

  const long base = ((long)b * Cn + c) * Tn;
  const float* px = x + base;
  const float* pm = m + base;
  const float* pd = d + base;

  // input schedule (verified): fwd step t reads idx max(t-1,0);
  // bwd step s reads idx min(T-s, T-1). Carry + aligned-quad prefetch.
  float cx, cm2, cd2;
  f32x4 qx, qm, qd;
  if (!dir) {
    cx = px[0]; cm2 = pm[0]; cd2 = pd[0];
    qx = *(const f32x4*)px; qm = *(const f32x4*)pm; qd = *(const f32x4*)pd;
  } else {
    cx = px[Tn - 1]; cm2 = pm[Tn - 1]; cd2 = pd[Tn - 1];
    qx = *(const f32x4*)(px + Tn - 4);
    qm = *(const f32x4*)(pm + Tn - 4);
    qd = *(const f32x4*)(pd + Tn - 4);
  }

  for (int t0 = 0; t0 < Tn; t0 += 4) {
    int qn_ = dir ? (Tn - 8 - t0) : (t0 + 4);
    if (qn_ < 0) qn_ = 0;
    if (qn_ > Tn - 4) qn_ = Tn - 4;
    const f32x4 nqx = *(const f32x4*)(px + qn_);
    const f32x4 nqm = *(const f32x4*)(pm + qn_);
    const f32x4 nqd = *(const f32x4*)(pd + qn_);

    float inx[4], inm[4], ind[4];
    if (!dir) {
      inx[0] = cx;  inx[1] = qx.x; inx[2] = qx.y; inx[3] = qx.z; cx  = qx.w;
      inm[0] = cm2; inm[1] = qm.x; inm[2] = qm.y; inm[3] = qm.z; cm2 = qm.w;
      ind[0] = cd2; ind[1] = qd.x; ind[2] = qd.y; ind[3] = qd.z; cd2 = qd.w;
    } else {
      inx[0] = cx;  inx[1] = qx.w; inx[2] = qx.z; inx[3] = qx.y; cx  = qx.x;
      inm[0] = cm2; inm[1] = qm.w; inm[2] = qm.z; inm[3] = qm.y; cm2 = qm.x;
      ind[0] = cd2; ind[1] = qd.w; ind[2] = qd.z; ind[3] = qd.y; cd2 = qd.x;
    }

    f32x4 pacc;
#pragma unroll
    for (int u = 0; u < 4; ++u) {
      const float ix = inx[u], im = inm[u], idv = ind[u];
      f32x4 vi0, vi1;
#pragma unroll
      for (int r = 0; r < 4; ++r) {
        vi0[r] = fmaf(v0x[r], ix, fmaf(v0y[r], im, fmaf(v0z[r], idv, bs0[r])));
        vi1[r] = fmaf(v1x[r], ix, fmaf(v1y[r], im, fmaf(v1z[r], idv, bs1[r])));
      }
      const short8 bh = __builtin_bit_cast(short8, Bh);
      const short8 bl = __builtin_bit_cast(short8, Bl);
      // two independent accumulator chains per tile (depth 2, 4-way ILP)
      f32x4 s0 = __builtin_amdgcn_mfma_f32_16x16x32_bf16(A0l, bh, z4, 0, 0, 0);
      f32x4 s1 = __builtin_amdgcn_mfma_f32_16x16x32_bf16(A1l, bh, z4, 0, 0, 0);
      f32x4 a0 = __builtin_amdgcn_mfma_f32_16x16x32_bf16(A0h, bh, vi0, 0, 0, 0);
      f32x4 a1 = __builtin_amdgcn_mfma_f32_16x16x32_bf16(A1h, bh, vi1, 0, 0, 0);
      s0 = __builtin_amdgcn_mfma_f32_16x16x32_bf16(A0h, bl, s0, 0, 0, 0);
      s1 = __builtin_amdgcn_mfma_f32_16x16x32_bf16(A1h, bl, s1, 0, 0, 0);
      f32x4 h0, h1;
#pragma unroll
      for (int r = 0; r < 4; ++r) {
        h0[r] = fmaxf(a0[r] + s0[r], 0.f);
        h1[r] = fmaxf(a1[r] + s1[r], 0.f);
      }
      // U partial over this lane's 8 physical rows, reduce over q-lanes
      float p = uu0[0] * h0[0];
      p = fmaf(uu0[1], h0[1], p); p = fmaf(uu0[2], h0[2], p);
      p = fmaf(uu0[3], h0[3], p);
      p = fmaf(uu1[0], h1[0], p); p = fmaf(uu1[1], h1[1], p);
      p = fmaf(uu1[2], h1[2], p); p = fmaf(uu1[3], h1[3], p);
      p += __shfl_xor(p, 16);
      p += __shfl_xor(p, 32);
      pacc[dir ? (3 - u) : u] = p;
      // repack state: hi via v_perm, lo via exact residual + RNE + v_perm
      const unsigned h00 = __float_as_uint(h0[0]), h01 = __float_as_uint(h0[1]);
      const unsigned h02 = __float_as_uint(h0[2]), h03 = __float_as_uint(h0[3]);
      const unsigned h10 = __float_as_uint(h1[0]), h11 = __float_as_uint(h1[1]);
      const unsigned h12 = __float_as_uint(h1[2]), h13 = __float_as_uint(h1[3]);
      Bh[0] = pk_hi(h01, h00); Bh[1] = pk_hi(h03, h02);
      Bh[2] = pk_hi(h11, h10); Bh[3] = pk_hi(h13, h12);
      unsigned ru[8];
#pragma unroll
      for (int r = 0; r < 4; ++r) {
        ru[r]     = __float_as_uint(h0[r] - __uint_as_float(__float_as_uint(h0[r]) & 0xffff0000u)) + 0x8000u;
        ru[4 + r] = __float_as_uint(h1[r] - __uint_as_float(__float_as_uint(h1[r]) & 0xffff0000u)) + 0x8000u;
      }
      Bl[0] = pk_hi(ru[1], ru[0]); Bl[1] = pk_hi(ru[3], ru[2]);
      Bl[2] = pk_hi(ru[5], ru[4]); Bl[3] = pk_hi(ru[7], ru[6]);
    }
    if (q == 0) {
      float* dst = &pbuf[dir][n][dir ? (Tn - 4 - t0) : t0];  // bwd pre-reversed
      *(f32x4*)dst = pacc;
    }
    qx = nqx; qm = nqm; qd = nqd;
  }

  __syncthreads();

  // ---- fused combine: out[b,c,t] = relu(pf + pb + c0[c])
  const float c0v = c0[c];
#pragma unroll
  for (int i = 0; i < 8; ++i) {
    const int nn = 2 * i + (tid >> 6);
    const int tt = (tid & 63) << 2;
    const f32x4 pf  = *(const f32x4*)&pbuf[0][nn][tt];
    const f32x4 pbv = *(const f32x4*)&pbuf[1][nn][tt];
    f32x4 o;
#pragma unroll
    for (int e = 0; e < 4; ++e) o[e] = fmaxf(pf[e] + pbv[e] + c0v, 0.f);
    *(f32x4*)(out + (((long)((g * 16 + nn) * Cn + c)) << 8) + tt) = o;
  }
}

extern "C" void kernel_launch(void* const* d_in, const int* in_sizes, int n_in,
                              void* d_out, int out_size, void* d_ws, size_t ws_size,
                              hipStream_t stream) {
  const float* x  = (const float*)d_in[0];
  const float* m  = (const float*)d_in[1];
  const float* dd = (const float*)d_in[2];
  const float* Wf = (const float*)d_in[3];
  const float* Vf = (const float*)d_in[4];
  const float* cf = (const float*)d_in[5];
  const float* Wb = (const float*)d_in[6];
  const float* Vb = (const float*)d_in[7];
  const float* cb = (const float*)d_in[8];
  const float* U  = (const float*)d_in[9];
  const float* c0 = (const float*)d_in[10];
  float* out = (float*)d_out;

  mrnn_fused<<<512, 128, 0, stream>>>(x, m, dd, Wf, Vf, cf, Wb, Vb, cb, U, c0, out);
}

// Round 5
// 160.728 us; speedup vs baseline: 1.2937x; 1.2937x over previous
//
#include <hip/hip_runtime.h>

// mRNN B=128, C=64, H=32, T=256 via MFMA 16x16x32 bf16, split-bf16 (hi+lo).
// R3 structure (fastest so far): 1024 single-wave blocks, one wave per
// (dir, c, batch-group-16). __launch_bounds__(64,1) grants the full 512-VGPR
// budget: R1/R3/R4 showed the compiler capping VGPRs (68-92) and shunting
// loop invariants into AGPRs, paying v_accvgpr_read/write inside the t-loop.
// Grid is 1024 waves = exactly 1 wave/SIMD, so occupancy is unaffected.
//
// Layout-closed recurrence (R3-verified): h kept as the B-operand fragment;
// row perm rho(m)=8*(m>>2)+(m&3) (+4 for tile1) makes lane (q,n)'s C/D
// output exactly its next-step B fragment. No LDS / cross-lane in the loop.
//
// Precision (R3/R4-verified, absmax 4096 < 15155 thr): W=Whi+Wlo, h=hhi+hlo,
// hi=truncate (exact residual), lo=RNE; D = vinit + Whi@hl + Wlo@hh + Whi@hh.
constexpr int Bn = 128, Cn = 64, Hn = 32, Tn = 256;

typedef __attribute__((ext_vector_type(8))) short short8;
typedef __attribute__((ext_vector_type(4))) float f32x4;
typedef __attribute__((ext_vector_type(4))) unsigned int u32x4;

// pack top16(y):top16(x) -> one u32 (low half = x's top16)
__device__ __forceinline__ unsigned pk_hi(unsigned y, unsigned x) {
  return __builtin_amdgcn_perm(y, x, 0x07060302u);
}

__device__ __forceinline__ void wsplit(float w, short& hi, short& lo) {
  unsigned u = __float_as_uint(w);
  float r = w - __uint_as_float(u & 0xffff0000u);   // exact residual
  unsigned ru = __float_as_uint(r) + 0x8000u;       // RNE-ish lo
  hi = (short)(u >> 16);
  lo = (short)(ru >> 16);
}

__global__ __launch_bounds__(64, 1)
void mrnn_scan(const float* __restrict__ x, const float* __restrict__ m,
               const float* __restrict__ d,
               const float* __restrict__ Wf, const float* __restrict__ Vf,
               const float* __restrict__ cf,
               const float* __restrict__ Wb, const float* __restrict__ Vb,
               const float* __restrict__ cb,
               const float* __restrict__ U,
               float* __restrict__ pf_out, float* __restrict__ pb_out) {
  const int bid = blockIdx.x;
  const int dir = bid >> 9;                 // 0 fwd, 1 bwd
  const int c   = (bid >> 3) & (Cn - 1);
  const int g   = bid & 7;                  // batch group of 16
  const int tid = threadIdx.x;              // 0..63, one wave
  const int q = tid >> 4;
  const int n = tid & 15;
  const int b = g * 16 + n;

  const float* W  = dir ? Wb : Wf;
  const float* V  = dir ? Vb : Vf;
  const float* cc = dir ? cb : cf;

  // ---- A fragments: A[m=lane&15][k=8q+j], row perm rho(m)=8*(m>>2)+(m&3)
  const int ra0 = 8 * (n >> 2) + (n & 3);
  const int ra1 = ra0 + 4;
  short8 A0h, A0l, A1h, A1l;
#pragma unroll
  for (int j = 0; j < 8; ++j) {
    short hi, lo;
    wsplit(W[(c * Hn + ra0) * Hn + 8 * q + j], hi, lo); A0h[j] = hi; A0l[j] = lo;
    wsplit(W[(c * Hn + ra1) * Hn + 8 * q + j], hi, lo); A1h[j] = hi; A1l[j] = lo;
  }

  // ---- per-lane D rows: tile0 -> 8q+r, tile1 -> 8q+4+r
  float v0x[4], v0y[4], v0z[4], bs0[4], uu0[4];
  float v1x[4], v1y[4], v1z[4], bs1[4], uu1[4];
#pragma unroll
  for (int r = 0; r < 4; ++r) {
    const int row0 = 8 * q + r, row1 = row0 + 4;
    const float* vp0 = V + (c * Hn + row0) * 3;
    v0x[r] = vp0[0]; v0y[r] = vp0[1]; v0z[r] = vp0[2];
    bs0[r] = cc[c * Hn + row0];
    uu0[r] = U[c * 2 * Hn + dir * Hn + row0];
    const float* vp1 = V + (c * Hn + row1) * 3;
    v1x[r] = vp1[0]; v1y[r] = vp1[1]; v1z[r] = vp1[2];
    bs1[r] = cc[c * Hn + row1];
    uu1[r] = U[c * 2 * Hn + dir * Hn + row1];
  }

  // ---- state (B fragments)
  u32x4 Bh = {0u, 0u, 0u, 0u};
  u32x4 Bl = {0u, 0u, 0u, 0u};

  const long base = ((long)b * Cn + c) * Tn;
  const float* px = x + base;
  const float* pm = m + base;
  const float* pd = d + base;
  float* pout = (dir ? pb_out : pf_out) + base;

  // input schedule (verified): fwd step t reads idx max(t-1,0);
  // bwd step s reads idx min(T-s, T-1). Carry + aligned-quad prefetch.
  float cx, cm2, cd2;
  f32x4 qx, qm, qd;
  if (!dir) {
    cx = px[0]; cm2 = pm[0]; cd2 = pd[0];
    qx = *(const f32x4*)px; qm = *(const f32x4*)pm; qd = *(const f32x4*)pd;
  } else {
    cx = px[Tn - 1]; cm2 = pm[Tn - 1]; cd2 = pd[Tn - 1];
    qx = *(const f32x4*)(px + Tn - 4);
    qm = *(const f32x4*)(pm + Tn - 4);
    qd = *(const f32x4*)(pd + Tn - 4);
  }

  for (int t0 = 0; t0 < Tn; t0 += 4) {
    int qn_ = dir ? (Tn - 8 - t0) : (t0 + 4);
    if (qn_ < 0) qn_ = 0;
    if (qn_ > Tn - 4) qn_ = Tn - 4;
    const f32x4 nqx = *(const f32x4*)(px + qn_);
    const f32x4 nqm = *(const f32x4*)(pm + qn_);
    const f32x4 nqd = *(const f32x4*)(pd + qn_);

    float inx[4], inm[4], ind[4];
    if (!dir) {
      inx[0] = cx;  inx[1] = qx.x; inx[2] = qx.y; inx[3] = qx.z; cx  = qx.w;
      inm[0] = cm2; inm[1] = qm.x; inm[2] = qm.y; inm[3] = qm.z; cm2 = qm.w;
      ind[0] = cd2; ind[1] = qd.x; ind[2] = qd.y; ind[3] = qd.z; cd2 = qd.w;
    } else {
      inx[0] = cx;  inx[1] = qx.w; inx[2] = qx.z; inx[3] = qx.y; cx  = qx.x;
      inm[0] = cm2; inm[1] = qm.w; inm[2] = qm.z; inm[3] = qm.y; cm2 = qm.x;
      ind[0] = cd2; ind[1] = qd.w; ind[2] = qd.z; ind[3] = qd.y; cd2 = qd.x;
    }

    f32x4 pacc;
#pragma unroll
    for (int u = 0; u < 4; ++u) {
      const float ix = inx[u], im = inm[u], idv = ind[u];
      f32x4 acc0, acc1;
#pragma unroll
      for (int r = 0; r < 4; ++r) {
        acc0[r] = fmaf(v0x[r], ix, fmaf(v0y[r], im, fmaf(v0z[r], idv, bs0[r])));
        acc1[r] = fmaf(v1x[r], ix, fmaf(v1y[r], im, fmaf(v1z[r], idv, bs1[r])));
      }
      const short8 bh = __builtin_bit_cast(short8, Bh);
      const short8 bl = __builtin_bit_cast(short8, Bl);
      // depth-3 chain per tile, 2 tiles give 2-way ILP; big hi@hh term last
      acc0 = __builtin_amdgcn_mfma_f32_16x16x32_bf16(A0l, bh, acc0, 0, 0, 0);
      acc1 = __builtin_amdgcn_mfma_f32_16x16x32_bf16(A1l, bh, acc1, 0, 0, 0);
      acc0 = __builtin_amdgcn_mfma_f32_16x16x32_bf16(A0h, bl, acc0, 0, 0, 0);
      acc1 = __builtin_amdgcn_mfma_f32_16x16x32_bf16(A1h, bl, acc1, 0, 0, 0);
      acc0 = __builtin_amdgcn_mfma_f32_16x16x32_bf16(A0h, bh, acc0, 0, 0, 0);
      acc1 = __builtin_amdgcn_mfma_f32_16x16x32_bf16(A1h, bh, acc1, 0, 0, 0);
#pragma unroll
      for (int r = 0; r < 4; ++r) {
        acc0[r] = fmaxf(acc0[r], 0.f);
        acc1[r] = fmaxf(acc1[r], 0.f);
      }
      // U partial over this lane's 8 physical rows, reduce over q-lanes
      float p = uu0[0] * acc0[0];
      p = fmaf(uu0[1], acc0[1], p); p = fmaf(uu0[2], acc0[2], p);
      p = fmaf(uu0[3], acc0[3], p);
      p = fmaf(uu1[0], acc1[0], p); p = fmaf(uu1[1], acc1[1], p);
      p = fmaf(uu1[2], acc1[2], p); p = fmaf(uu1[3], acc1[3], p);
      p += __shfl_xor(p, 16);
      p += __shfl_xor(p, 32);
      pacc[u] = p;
      // repack state: hi = truncate via v_perm; lo = exact residual + RNE
      const unsigned h00 = __float_as_uint(acc0[0]), h01 = __float_as_uint(acc0[1]);
      const unsigned h02 = __float_as_uint(acc0[2]), h03 = __float_as_uint(acc0[3]);
      const unsigned h10 = __float_as_uint(acc1[0]), h11 = __float_as_uint(acc1[1]);
      const unsigned h12 = __float_as_uint(acc1[2]), h13 = __float_as_uint(acc1[3]);
      Bh[0] = pk_hi(h01, h00); Bh[1] = pk_hi(h03, h02);
      Bh[2] = pk_hi(h11, h10); Bh[3] = pk_hi(h13, h12);
      unsigned ru[8];
#pragma unroll
      for (int r = 0; r < 4; ++r) {
        ru[r]     = __float_as_uint(acc0[r] - __uint_as_float(__float_as_uint(acc0[r]) & 0xffff0000u)) + 0x8000u;
        ru[4 + r] = __float_as_uint(acc1[r] - __uint_as_float(__float_as_uint(acc1[r]) & 0xffff0000u)) + 0x8000u;
      }
      Bl[0] = pk_hi(ru[1], ru[0]); Bl[1] = pk_hi(ru[3], ru[2]);
      Bl[2] = pk_hi(ru[5], ru[4]); Bl[3] = pk_hi(ru[7], ru[6]);
    }
    if (q == 0) {
      if (!dir) {
        *(f32x4*)(pout + t0) = pacc;
      } else {
        f32x4 rev = {pacc[3], pacc[2], pacc[1], pacc[0]};
        *(f32x4*)(pout + (Tn - 4 - t0)) = rev;       // pre-reversed
      }
    }
    qx = nqx; qm = nqm; qd = nqd;
  }
}

// out[i] = relu(pf[i] + pb[i] + c0[c]); pf staged in d_out, pb pre-reversed.
__global__ __launch_bounds__(256)
void mrnn_combine(const float* __restrict__ pb, const float* __restrict__ c0,
                  float* __restrict__ out) {
  const int i4 = blockIdx.x * 256 + threadIdx.x;
  const int c = (i4 >> 6) & (Cn - 1);
  const float c0v = c0[c];
  float4 a = ((const float4*)out)[i4];
  const float4 bb = ((const float4*)pb)[i4];
  a.x = fmaxf(a.x + bb.x + c0v, 0.f);
  a.y = fmaxf(a.y + bb.y + c0v, 0.f);
  a.z = fmaxf(a.z + bb.z + c0v, 0.f);
  a.w = fmaxf(a.w + bb.w + c0v, 0.f);
  ((float4*)out)[i4] = a;
}

extern "C" void kernel_launch(void* const* d_in, const int* in_sizes, int n_in,
                              void* d_out, int out_size, void* d_ws, size_t ws_size,
                              hipStream_t stream) {
  const float* x  = (const float*)d_in[0];
  const float* m  = (const float*)d_in[1];
  const float* dd = (const float*)d_in[2];
  const float* Wf = (const float*)d_in[3];
  const float* Vf = (const float*)d_in[4];
  const float* cf = (const float*)d_in[5];
  const float* Wb = (const float*)d_in[6];
  const float* Vb = (const float*)d_in[7];
  const float* cb = (const float*)d_in[8];
  const float* U  = (const float*)d_in[9];
  const float* c0 = (const float*)d_in[10];
  float* out = (float*)d_out;
  float* pb  = (float*)d_ws;   // B*C*T floats = 8 MB scratch

  mrnn_scan<<<1024, 64, 0, stream>>>(x, m, dd, Wf, Vf, cf, Wb, Vb, cb, U, out, pb);
  mrnn_combine<<<(Bn * Cn * Tn) / (256 * 4), 256, 0, stream>>>(pb, c0, out);
}

// Round 8
// 157.838 us; speedup vs baseline: 1.3174x; 1.0183x over previous
//
#include <hip/hip_runtime.h>

// mRNN B=128, C=64, H=32, T=256 via MFMA 16x16x32 bf16, split-bf16 (hi+lo).
// R5 structure EXACTLY (runtime dir, single loop body): 1024 single-wave
// blocks, one wave per (dir, c, batch-group-16).
//
// R6/R7 lesson: the dir-templated dual-inline variant fails validation
// (absmax 65536/36864 vs R5's 4096) even when arithmetic is bit-identical
// to R5 -> suspected codegen issue in the doubled MFMA loop body. Stick to
// the single runtime-dir body (R3/R4/R5 all passed with it).
//
// R8 delta vs R5 (the ONLY change): cross-q output reduction batched per
// 4-step quad (4 independent xor-16 swizzles, then 4 xor-32) instead of 2
// serial DS round-trips inside every step. Arithmetic values identical.
//
// Layout-closed recurrence (R3/R5-verified): h kept as the B-operand
// fragment; row perm rho(m)=8*(m>>2)+(m&3) (+4 tile1) makes lane (q,n)'s
// C/D output exactly its next-step B fragment. No LDS in the recurrence.
//
// Precision (R5-verified, absmax 4096 < 15155 thr): W=Whi+Wlo, h=hhi+hlo,
// hi=truncate (exact residual), lo=RNE; D = vinit + Whi@hl + Wlo@hh + Whi@hh.
constexpr int Bn = 128, Cn = 64, Hn = 32, Tn = 256;

typedef __attribute__((ext_vector_type(8))) short short8;
typedef __attribute__((ext_vector_type(4))) float f32x4;
typedef __attribute__((ext_vector_type(4))) unsigned int u32x4;

// pack top16(y):top16(x) -> one u32 (low half = x's top16)
__device__ __forceinline__ unsigned pk_hi(unsigned y, unsigned x) {
  return __builtin_amdgcn_perm(y, x, 0x07060302u);
}

__device__ __forceinline__ void wsplit(float w, short& hi, short& lo) {
  unsigned u = __float_as_uint(w);
  float r = w - __uint_as_float(u & 0xffff0000u);   // exact residual
  unsigned ru = __float_as_uint(r) + 0x8000u;       // RNE-ish lo
  hi = (short)(u >> 16);
  lo = (short)(ru >> 16);
}

__global__ __launch_bounds__(64, 1)
void mrnn_scan(const float* __restrict__ x, const float* __restrict__ m,
               const float* __restrict__ d,
               const float* __restrict__ Wf, const float* __restrict__ Vf,
               const float* __restrict__ cf,
               const float* __restrict__ Wb, const float* __restrict__ Vb,
               const float* __restrict__ cb,
               const float* __restrict__ U,
               float* __restrict__ pf_out, float* __restrict__ pb_out) {
  const int bid = blockIdx.x;
  const int dir = bid >> 9;                 // 0 fwd, 1 bwd
  const int c   = (bid >> 3) & (Cn - 1);
  const int g   = bid & 7;                  // batch group of 16
  const int tid = threadIdx.x;              // 0..63, one wave
  const int q = tid >> 4;
  const int n = tid & 15;
  const int b = g * 16 + n;

  const float* W  = dir ? Wb : Wf;
  const float* V  = dir ? Vb : Vf;
  const float* cc = dir ? cb : cf;

  // ---- A fragments: A[m=lane&15][k=8q+j], row perm rho(m)=8*(m>>2)+(m&3)
  const int ra0 = 8 * (n >> 2) + (n & 3);
  const int ra1 = ra0 + 4;
  short8 A0h, A0l, A1h, A1l;
#pragma unroll
  for (int j = 0; j < 8; ++j) {
    short hi, lo;
    wsplit(W[(c * Hn + ra0) * Hn + 8 * q + j], hi, lo); A0h[j] = hi; A0l[j] = lo;
    wsplit(W[(c * Hn + ra1) * Hn + 8 * q + j], hi, lo); A1h[j] = hi; A1l[j] = lo;
  }

  // ---- per-lane D rows: tile0 -> 8q+r, tile1 -> 8q+4+r
  float v0x[4], v0y[4], v0z[4], bs0[4], uu0[4];
  float v1x[4], v1y[4], v1z[4], bs1[4], uu1[4];
#pragma unroll
  for (int r = 0; r < 4; ++r) {
    const int row0 = 8 * q + r, row1 = row0 + 4;
    const float* vp0 = V + (c * Hn + row0) * 3;
    v0x[r] = vp0[0]; v0y[r] = vp0[1]; v0z[r] = vp0[2];
    bs0[r] = cc[c * Hn + row0];
    uu0[r] = U[c * 2 * Hn + dir * Hn + row0];
    const float* vp1 = V + (c * Hn + row1) * 3;
    v1x[r] = vp1[0]; v1y[r] = vp1[1]; v1z[r] = vp1[2];
    bs1[r] = cc[c * Hn + row1];
    uu1[r] = U[c * 2 * Hn + dir * Hn + row1];
  }

  // ---- state (B fragments)
  u32x4 Bh = {0u, 0u, 0u, 0u};
  u32x4 Bl = {0u, 0u, 0u, 0u};

  const long base = ((long)b * Cn + c) * Tn;
  const float* px = x + base;
  const float* pm = m + base;
  const float* pd = d + base;
  float* pout = (dir ? pb_out : pf_out) + base;

  // input schedule (verified): fwd step t reads idx max(t-1,0);
  // bwd step s reads idx min(T-s, T-1). Carry + aligned-quad prefetch.
  float cx, cm2, cd2;
  f32x4 qx, qm, qd;
  if (!dir) {
    cx = px[0]; cm2 = pm[0]; cd2 = pd[0];
    qx = *(const f32x4*)px; qm = *(const f32x4*)pm; qd = *(const f32x4*)pd;
  } else {
    cx = px[Tn - 1]; cm2 = pm[Tn - 1]; cd2 = pd[Tn - 1];
    qx = *(const f32x4*)(px + Tn - 4);
    qm = *(const f32x4*)(pm + Tn - 4);
    qd = *(const f32x4*)(pd + Tn - 4);
  }

  for (int t0 = 0; t0 < Tn; t0 += 4) {
    int qn_ = dir ? (Tn - 8 - t0) : (t0 + 4);
    if (qn_ < 0) qn_ = 0;
    if (qn_ > Tn - 4) qn_ = Tn - 4;
    const f32x4 nqx = *(const f32x4*)(px + qn_);
    const f32x4 nqm = *(const f32x4*)(pm + qn_);
    const f32x4 nqd = *(const f32x4*)(pd + qn_);

    float inx[4], inm[4], ind[4];
    if (!dir) {
      inx[0] = cx;  inx[1] = qx.x; inx[2] = qx.y; inx[3] = qx.z;
      inm[0] = cm2; inm[1] = qm.x; inm[2] = qm.y; inm[3] = qm.z;
      ind[0] = cd2; ind[1] = qd.x; ind[2] = qd.y; ind[3] = qd.z;
      cx = qx.w; cm2 = qm.w; cd2 = qd.w;
    } else {
      inx[0] = cx;  inx[1] = qx.w; inx[2] = qx.z; inx[3] = qx.y;
      inm[0] = cm2; inm[1] = qm.w; inm[2] = qm.z; inm[3] = qm.y;
      ind[0] = cd2; ind[1] = qd.w; ind[2] = qd.z; ind[3] = qd.y;
      cx = qx.x; cm2 = qm.x; cd2 = qd.x;
    }

    f32x4 pacc;
#pragma unroll
    for (int u = 0; u < 4; ++u) {
      const float ix = inx[u], im = inm[u], idv = ind[u];
      f32x4 acc0, acc1;
#pragma unroll
      for (int r = 0; r < 4; ++r) {
        acc0[r] = fmaf(v0x[r], ix, fmaf(v0y[r], im, fmaf(v0z[r], idv, bs0[r])));
        acc1[r] = fmaf(v1x[r], ix, fmaf(v1y[r], im, fmaf(v1z[r], idv, bs1[r])));
      }
      const short8 bh = __builtin_bit_cast(short8, Bh);
      const short8 bl = __builtin_bit_cast(short8, Bl);
      // depth-3 chain per tile, 2 tiles give 2-way ILP; big hi@hh term last
      acc0 = __builtin_amdgcn_mfma_f32_16x16x32_bf16(A0l, bh, acc0, 0, 0, 0);
      acc1 = __builtin_amdgcn_mfma_f32_16x16x32_bf16(A1l, bh, acc1, 0, 0, 0);
      acc0 = __builtin_amdgcn_mfma_f32_16x16x32_bf16(A0h, bl, acc0, 0, 0, 0);
      acc1 = __builtin_amdgcn_mfma_f32_16x16x32_bf16(A1h, bl, acc1, 0, 0, 0);
      acc0 = __builtin_amdgcn_mfma_f32_16x16x32_bf16(A0h, bh, acc0, 0, 0, 0);
      acc1 = __builtin_amdgcn_mfma_f32_16x16x32_bf16(A1h, bh, acc1, 0, 0, 0);
#pragma unroll
      for (int r = 0; r < 4; ++r) {
        acc0[r] = fmaxf(acc0[r], 0.f);
        acc1[r] = fmaxf(acc1[r], 0.f);
      }
      // per-lane U partial (fp32); cross-q reduction deferred to quad end
      float p = uu0[0] * acc0[0];
      p = fmaf(uu0[1], acc0[1], p); p = fmaf(uu0[2], acc0[2], p);
      p = fmaf(uu0[3], acc0[3], p);
      p = fmaf(uu1[0], acc1[0], p); p = fmaf(uu1[1], acc1[1], p);
      p = fmaf(uu1[2], acc1[2], p); p = fmaf(uu1[3], acc1[3], p);
      pacc[u] = p;
      // repack state: hi = truncate via v_perm; lo = exact residual + RNE
      const unsigned h00 = __float_as_uint(acc0[0]), h01 = __float_as_uint(acc0[1]);
      const unsigned h02 = __float_as_uint(acc0[2]), h03 = __float_as_uint(acc0[3]);
      const unsigned h10 = __float_as_uint(acc1[0]), h11 = __float_as_uint(acc1[1]);
      const unsigned h12 = __float_as_uint(acc1[2]), h13 = __float_as_uint(acc1[3]);
      Bh[0] = pk_hi(h01, h00); Bh[1] = pk_hi(h03, h02);
      Bh[2] = pk_hi(h11, h10); Bh[3] = pk_hi(h13, h12);
      unsigned ru[8];
#pragma unroll
      for (int r = 0; r < 4; ++r) {
        ru[r]     = __float_as_uint(acc0[r] - __uint_as_float(__float_as_uint(acc0[r]) & 0xffff0000u)) + 0x8000u;
        ru[4 + r] = __float_as_uint(acc1[r] - __uint_as_float(__float_as_uint(acc1[r]) & 0xffff0000u)) + 0x8000u;
      }
      Bl[0] = pk_hi(ru[1], ru[0]); Bl[1] = pk_hi(ru[3], ru[2]);
      Bl[2] = pk_hi(ru[5], ru[4]); Bl[3] = pk_hi(ru[7], ru[6]);
    }
    // batched cross-q reduction: 4 independent xor-16, then 4 xor-32
    // (one DS latency window per quad instead of 2 serial per step)
#pragma unroll
    for (int u = 0; u < 4; ++u) pacc[u] += __shfl_xor(pacc[u], 16);
#pragma unroll
    for (int u = 0; u < 4; ++u) pacc[u] += __shfl_xor(pacc[u], 32);

    if (q == 0) {
      if (!dir) {
        *(f32x4*)(pout + t0) = pacc;
      } else {
        f32x4 rev = {pacc[3], pacc[2], pacc[1], pacc[0]};
        *(f32x4*)(pout + (Tn - 4 - t0)) = rev;       // pre-reversed
      }
    }
    qx = nqx; qm = nqm; qd = nqd;
  }
}

// out[i] = relu(pf[i] + pb[i] + c0[c]); pf staged in d_out, pb pre-reversed.
__global__ __launch_bounds__(256)
void mrnn_combine(const float* __restrict__ pb, const float* __restrict__ c0,
                  float* __restrict__ out) {
  const int i4 = blockIdx.x * 256 + threadIdx.x;
  const int c = (i4 >> 6) & (Cn - 1);
  const float c0v = c0[c];
  float4 a = ((const float4*)out)[i4];
  const float4 bb = ((const float4*)pb)[i4];
  a.x = fmaxf(a.x + bb.x + c0v, 0.f);
  a.y = fmaxf(a.y + bb.y + c0v, 0.f);
  a.z = fmaxf(a.z + bb.z + c0v, 0.f);
  a.w = fmaxf(a.w + bb.w + c0v, 0.f);
  ((float4*)out)[i4] = a;
}

extern "C" void kernel_launch(void* const* d_in, const int* in_sizes, int n_in,
                              void* d_out, int out_size, void* d_ws, size_t ws_size,
                              hipStream_t stream) {
  const float* x  = (const float*)d_in[0];
  const float* m  = (const float*)d_in[1];
  const float* dd = (const float*)d_in[2];
  const float* Wf = (const float*)d_in[3];
  const float* Vf = (const float*)d_in[4];
  const float* cf = (const float*)d_in[5];
  const float* Wb = (const float*)d_in[6];
  const float* Vb = (const float*)d_in[7];
  const float* cb = (const float*)d_in[8];
  const float* U  = (const float*)d_in[9];
  const float* c0 = (const float*)d_in[10];
  float* out = (float*)d_out;
  float* pb  = (float*)d_ws;   // B*C*T floats = 8 MB scratch

  mrnn_scan<<<1024, 64, 0, stream>>>(x, m, dd, Wf, Vf, cf, Wb, Vb, cb, U, out, pb);
  mrnn_combine<<<(Bn * Cn * Tn) / (256 * 4), 256, 0, stream>>>(pb, c0, out);
}